// Round 1
// baseline (124.433 us; speedup 1.0000x reference)
//
#include <hip/hip_runtime.h>
#include <hip/hip_bf16.h>

#define N 8192
#define D 128
#define WEIGHT 0.01f

typedef __bf16 bf16x8 __attribute__((ext_vector_type(8)));
typedef float floatx4 __attribute__((ext_vector_type(4)));

// ---- Kernel 1: L2-normalize rows (fp32), store bf16; zero A/Col accumulators.
__global__ __launch_bounds__(256) void k_norm(const float* __restrict__ x,
                                              __hip_bfloat16* __restrict__ fb,
                                              float* __restrict__ Arow,
                                              float* __restrict__ Acol) {
    int gid = blockIdx.x * 256 + threadIdx.x;   // 2048 blocks -> 524288 threads = 8192 waves
    if (gid < N) { Arow[gid] = 0.0f; Acol[gid] = 0.0f; }
    int row = gid >> 6;
    int lane = gid & 63;
    const float* xr = x + row * D;
    float a0 = xr[lane];
    float a1 = xr[lane + 64];
    float s = a0 * a0 + a1 * a1;
    #pragma unroll
    for (int m = 1; m < 64; m <<= 1) s += __shfl_xor(s, m, 64);
    float inv = 1.0f / fmaxf(sqrtf(s), 1e-12f);
    fb[row * D + lane]      = __float2bfloat16(a0 * inv);
    fb[row * D + lane + 64] = __float2bfloat16(a1 * inv);
}

// ---- Kernel 2: p[i] = f_i . f_{i+1} (bf16 inputs, fp32 acc), ep[i] = exp(p[i])
__global__ __launch_bounds__(256) void k_pos(const __hip_bfloat16* __restrict__ fb,
                                             float* __restrict__ p,
                                             float* __restrict__ ep) {
    int gid = blockIdx.x * 256 + threadIdx.x;
    int i = gid >> 6;
    int lane = gid & 63;
    if (i >= N - 1) return;
    float a0 = __bfloat162float(fb[i * D + lane]);
    float a1 = __bfloat162float(fb[i * D + lane + 64]);
    float b0 = __bfloat162float(fb[(i + 1) * D + lane]);
    float b1 = __bfloat162float(fb[(i + 1) * D + lane + 64]);
    float s = a0 * b0 + a1 * b1;
    #pragma unroll
    for (int m = 1; m < 64; m <<= 1) s += __shfl_xor(s, m, 64);
    if (lane == 0) { p[i] = s; ep[i] = __expf(s); }
}

// ---- Kernel 3: upper-triangle 128x128 tiles of sim = F F^T; accumulate
//      Arow[r] += sum_{c>r} exp(sim[r,c]), Acol[c] += sum_{r<c} exp(sim[r,c]).
__global__ __launch_bounds__(256, 2) void k_gram(const __hip_bfloat16* __restrict__ fb,
                                                 float* __restrict__ Arow,
                                                 float* __restrict__ Acol) {
    const int bi = blockIdx.y;
    const int bj = blockIdx.x;
    if (bj < bi) return;                 // upper triangle of tiles only
    __shared__ uint4 Ab[128 * 16];       // 128 rows x 128 bf16 (16 uint4), XOR-swizzled
    __shared__ uint4 Bb[128 * 16];
    const int t = threadIdx.x;
    const int rbase = bi * 128, cbase = bj * 128;
    const uint4* g = (const uint4*)fb;   // row stride = 16 uint4 (D=128 bf16)
    #pragma unroll
    for (int k = 0; k < 8; ++k) {
        int idx = t + k * 256;           // 0..2047
        int row = idx >> 4, c16 = idx & 15;
        int sw = c16 ^ (row & 15);       // XOR swizzle breaks 256B-stride bank aliasing
        Ab[row * 16 + sw] = g[(rbase + row) * 16 + c16];
        Bb[row * 16 + sw] = g[(cbase + row) * 16 + c16];
    }
    __syncthreads();

    const int lane = t & 63;
    const int wid  = t >> 6;             // 4 waves: 2x2 grid of 64x64 sub-tiles
    const int wrow = wid >> 1, wcol = wid & 1;
    const int col0 = lane & 15;
    const int quad = lane >> 4;

    floatx4 acc[4][4];
    #pragma unroll
    for (int a = 0; a < 4; ++a)
        #pragma unroll
        for (int b = 0; b < 4; ++b)
            acc[a][b] = (floatx4){0.0f, 0.0f, 0.0f, 0.0f};

    #pragma unroll
    for (int ks = 0; ks < 4; ++ks) {     // K = 128 = 4 x 32
        bf16x8 af[4], bfr[4];
        int j = ks * 4 + quad;           // uint4 chunk index within row
        int jsw = j ^ col0;              // (row & 15) == col0 for all fragment rows
        #pragma unroll
        for (int mt = 0; mt < 4; ++mt) {
            int rl = wrow * 64 + mt * 16 + col0;   // A[m=lane&15][k=quad*8+j]
            af[mt] = *(const bf16x8*)&Ab[rl * 16 + jsw];
        }
        #pragma unroll
        for (int nt = 0; nt < 4; ++nt) {
            int cl = wcol * 64 + nt * 16 + col0;   // B^T[n=lane&15][k]
            bfr[nt] = *(const bf16x8*)&Bb[cl * 16 + jsw];
        }
        #pragma unroll
        for (int mt = 0; mt < 4; ++mt)
            #pragma unroll
            for (int nt = 0; nt < 4; ++nt)
                acc[mt][nt] = __builtin_amdgcn_mfma_f32_16x16x32_bf16(af[mt], bfr[nt], acc[mt][nt], 0, 0, 0);
    }

    // Epilogue: e = exp(sim), keep strict upper (c > r), accumulate row/col partials.
    float rowpart[4][4];                 // [mt][reg] -> row = quad*4+reg
    float colpart[4];                    // [nt]      -> col = lane&15
    #pragma unroll
    for (int a = 0; a < 4; ++a) {
        colpart[a] = 0.0f;
        #pragma unroll
        for (int b = 0; b < 4; ++b) rowpart[a][b] = 0.0f;
    }

    #pragma unroll
    for (int mt = 0; mt < 4; ++mt) {
        #pragma unroll
        for (int nt = 0; nt < 4; ++nt) {
            #pragma unroll
            for (int reg = 0; reg < 4; ++reg) {
                int r = rbase + wrow * 64 + mt * 16 + quad * 4 + reg;  // C/D: row=quad*4+reg
                int c = cbase + wcol * 64 + nt * 16 + col0;            // C/D: col=lane&15
                float e = __expf(acc[mt][nt][reg]);
                e = (c > r) ? e : 0.0f;
                rowpart[mt][reg] += e;
                colpart[nt] += e;
            }
        }
    }

    // Row sums: reduce across the 16 lanes of each quad (xor 1,2,4,8).
    #pragma unroll
    for (int mt = 0; mt < 4; ++mt) {
        #pragma unroll
        for (int reg = 0; reg < 4; ++reg) {
            float v = rowpart[mt][reg];
            v += __shfl_xor(v, 1, 64);
            v += __shfl_xor(v, 2, 64);
            v += __shfl_xor(v, 4, 64);
            v += __shfl_xor(v, 8, 64);
            if (col0 == 0)
                atomicAdd(&Arow[rbase + wrow * 64 + mt * 16 + quad * 4 + reg], v);
        }
    }
    // Col sums: reduce across quads (xor 16, 32).
    #pragma unroll
    for (int nt = 0; nt < 4; ++nt) {
        float v = colpart[nt];
        v += __shfl_xor(v, 16, 64);
        v += __shfl_xor(v, 32, 64);
        if (quad == 0)
            atomicAdd(&Acol[cbase + wcol * 64 + nt * 16 + col0], v);
    }
}

// ---- Kernel 4: loss = sum_i log(A_i + Col_{i+1} - ep_i) - p_i; out = -W*loss/N
__global__ __launch_bounds__(256) void k_final(const float* __restrict__ Arow,
                                               const float* __restrict__ Acol,
                                               const float* __restrict__ p,
                                               const float* __restrict__ ep,
                                               float* __restrict__ out) {
    __shared__ float swred[4];
    float s = 0.0f;
    for (int i = threadIdx.x; i < N - 1; i += 256) {
        float tt = Arow[i] + Acol[i + 1] - ep[i];
        s += __logf(tt) - p[i];
    }
    #pragma unroll
    for (int m = 1; m < 64; m <<= 1) s += __shfl_xor(s, m, 64);
    int lane = threadIdx.x & 63, wid = threadIdx.x >> 6;
    if (lane == 0) swred[wid] = s;
    __syncthreads();
    if (threadIdx.x == 0) {
        float tot = swred[0] + swred[1] + swred[2] + swred[3];
        out[0] = -WEIGHT * tot / (float)N;
    }
}

extern "C" void kernel_launch(void* const* d_in, const int* in_sizes, int n_in,
                              void* d_out, int out_size, void* d_ws, size_t ws_size,
                              hipStream_t stream) {
    const float* x = (const float*)d_in[0];
    float* out = (float*)d_out;
    char* ws = (char*)d_ws;
    __hip_bfloat16* fb = (__hip_bfloat16*)ws;                  // N*D*2 = 2 MB
    float* p    = (float*)(ws + (size_t)N * D * 2);            // N floats
    float* ep   = p + N;
    float* Arow = ep + N;
    float* Acol = Arow + N;

    hipLaunchKernelGGL(k_norm,  dim3(2048),  dim3(256), 0, stream, x, fb, Arow, Acol);
    hipLaunchKernelGGL(k_pos,   dim3(2048),  dim3(256), 0, stream, fb, p, ep);
    hipLaunchKernelGGL(k_gram,  dim3(64, 64), dim3(256), 0, stream, fb, Arow, Acol);
    hipLaunchKernelGGL(k_final, dim3(1),     dim3(256), 0, stream, Arow, Acol, p, ep, out);
}

// Round 2
// 120.233 us; speedup vs baseline: 1.0349x; 1.0349x over previous
//
#include <hip/hip_runtime.h>
#include <hip/hip_bf16.h>

#define N 8192
#define D 128
#define WEIGHT 0.01f
#define NTILES 64            // N / 128

typedef __bf16 bf16x8 __attribute__((ext_vector_type(8)));
typedef float floatx4 __attribute__((ext_vector_type(4)));

// ---- Kernel 1: L2-normalize rows (fp32), store bf16; zero A/Col accumulators.
__global__ __launch_bounds__(256) void k_norm(const float* __restrict__ x,
                                              __hip_bfloat16* __restrict__ fb,
                                              float* __restrict__ Arow,
                                              float* __restrict__ Acol) {
    int gid = blockIdx.x * 256 + threadIdx.x;   // 2048 blocks -> 8192 waves
    if (gid < N) { Arow[gid] = 0.0f; Acol[gid] = 0.0f; }
    int row = gid >> 6;
    int lane = gid & 63;
    const float* xr = x + row * D;
    float a0 = xr[lane];
    float a1 = xr[lane + 64];
    float s = a0 * a0 + a1 * a1;
    #pragma unroll
    for (int m = 1; m < 64; m <<= 1) s += __shfl_xor(s, m, 64);
    float inv = 1.0f / fmaxf(sqrtf(s), 1e-12f);
    fb[row * D + lane]      = __float2bfloat16(a0 * inv);
    fb[row * D + lane + 64] = __float2bfloat16(a1 * inv);
}

// ---- Kernel 2: p[i] = f_i . f_{i+1} (bf16 inputs, fp32 acc), ep[i] = exp(p[i])
__global__ __launch_bounds__(256) void k_pos(const __hip_bfloat16* __restrict__ fb,
                                             float* __restrict__ p,
                                             float* __restrict__ ep) {
    int gid = blockIdx.x * 256 + threadIdx.x;
    int i = gid >> 6;
    int lane = gid & 63;
    if (i >= N - 1) return;
    float a0 = __bfloat162float(fb[i * D + lane]);
    float a1 = __bfloat162float(fb[i * D + lane + 64]);
    float b0 = __bfloat162float(fb[(i + 1) * D + lane]);
    float b1 = __bfloat162float(fb[(i + 1) * D + lane + 64]);
    float s = a0 * b0 + a1 * b1;
    #pragma unroll
    for (int m = 1; m < 64; m <<= 1) s += __shfl_xor(s, m, 64);
    if (lane == 0) { p[i] = s; ep[i] = __expf(s); }
}

// ---- Kernel 3: upper-triangle 128x128 tiles of sim = F F^T; accumulate
//      Arow[r] += sum_{c>r} exp(sim[r,c]), Acol[c] += sum_{r<c} exp(sim[r,c]).
//      512 threads = 8 waves (2 wrow x 4 wcol), wave tile 64x32.
//      LDS 64 KB -> 2 blocks/CU -> 16 waves/CU (50% occ).
__global__ __launch_bounds__(512, 4) void k_gram(const __hip_bfloat16* __restrict__ fb,
                                                 float* __restrict__ Arow,
                                                 float* __restrict__ Acol) {
    // Decode triangular linear index -> (bi, bj), bj >= bi, 64x64 tile grid.
    int b = blockIdx.x;                  // 0 .. 2079
    int bi = (int)((2.0 * NTILES + 1.0 - sqrt((2.0 * NTILES + 1.0) * (2.0 * NTILES + 1.0) - 8.0 * (double)b)) * 0.5);
    // integer fix-up (float-safe guard)
    while (bi * NTILES - bi * (bi - 1) / 2 > b) --bi;
    while ((bi + 1) * NTILES - (bi + 1) * bi / 2 <= b) ++bi;
    int bj = bi + (b - (bi * NTILES - bi * (bi - 1) / 2));

    __shared__ uint4 Ab[128 * 16];       // 128 rows x 128 bf16 (16 uint4), XOR-swizzled
    __shared__ uint4 Bb[128 * 16];
    const int t = threadIdx.x;
    const int rbase = bi * 128, cbase = bj * 128;
    const uint4* g = (const uint4*)fb;   // row stride = 16 uint4 (D=128 bf16)
    #pragma unroll
    for (int k = 0; k < 4; ++k) {
        int idx = t + k * 512;           // 0..2047
        int row = idx >> 4, c16 = idx & 15;
        int sw = c16 ^ (row & 15);       // XOR swizzle breaks 256B-stride bank aliasing
        Ab[row * 16 + sw] = g[(rbase + row) * 16 + c16];
        Bb[row * 16 + sw] = g[(cbase + row) * 16 + c16];
    }
    __syncthreads();

    const int lane = t & 63;
    const int wid  = t >> 6;             // 8 waves: 2x4 grid; wave tile 64 rows x 32 cols
    const int wrow = wid >> 2, wcol = wid & 3;
    const int col0 = lane & 15;
    const int quad = lane >> 4;

    floatx4 acc[4][2];
    #pragma unroll
    for (int a = 0; a < 4; ++a)
        #pragma unroll
        for (int c = 0; c < 2; ++c)
            acc[a][c] = (floatx4){0.0f, 0.0f, 0.0f, 0.0f};

    #pragma unroll
    for (int ks = 0; ks < 4; ++ks) {     // K = 128 = 4 x 32
        bf16x8 af[4], bfr[2];
        int j = ks * 4 + quad;           // uint4 chunk index within row
        int jsw = j ^ col0;              // (row & 15) == col0 for all fragment rows
        #pragma unroll
        for (int mt = 0; mt < 4; ++mt) {
            int rl = wrow * 64 + mt * 16 + col0;   // A[m=lane&15][k=quad*8+j]
            af[mt] = *(const bf16x8*)&Ab[rl * 16 + jsw];
        }
        #pragma unroll
        for (int nt = 0; nt < 2; ++nt) {
            int cl = wcol * 32 + nt * 16 + col0;   // B^T[n=lane&15][k]
            bfr[nt] = *(const bf16x8*)&Bb[cl * 16 + jsw];
        }
        #pragma unroll
        for (int mt = 0; mt < 4; ++mt)
            #pragma unroll
            for (int nt = 0; nt < 2; ++nt)
                acc[mt][nt] = __builtin_amdgcn_mfma_f32_16x16x32_bf16(af[mt], bfr[nt], acc[mt][nt], 0, 0, 0);
    }

    // Epilogue: e = exp(sim), keep strict upper (c > r), accumulate row/col partials.
    float rowpart[4][4];                 // [mt][reg] -> row = quad*4+reg
    float colpart[2];                    // [nt]      -> col = lane&15
    #pragma unroll
    for (int a = 0; a < 4; ++a)
        #pragma unroll
        for (int c = 0; c < 4; ++c) rowpart[a][c] = 0.0f;
    colpart[0] = colpart[1] = 0.0f;

    #pragma unroll
    for (int mt = 0; mt < 4; ++mt) {
        #pragma unroll
        for (int nt = 0; nt < 2; ++nt) {
            #pragma unroll
            for (int reg = 0; reg < 4; ++reg) {
                int r = rbase + wrow * 64 + mt * 16 + quad * 4 + reg;  // C/D: row=quad*4+reg
                int c = cbase + wcol * 32 + nt * 16 + col0;            // C/D: col=lane&15
                float e = __expf(acc[mt][nt][reg]);
                e = (c > r) ? e : 0.0f;
                rowpart[mt][reg] += e;
                colpart[nt] += e;
            }
        }
    }

    // Row sums: reduce across the 16 lanes of each quad (xor 1,2,4,8).
    #pragma unroll
    for (int mt = 0; mt < 4; ++mt) {
        #pragma unroll
        for (int reg = 0; reg < 4; ++reg) {
            float v = rowpart[mt][reg];
            v += __shfl_xor(v, 1, 64);
            v += __shfl_xor(v, 2, 64);
            v += __shfl_xor(v, 4, 64);
            v += __shfl_xor(v, 8, 64);
            if (col0 == 0)
                atomicAdd(&Arow[rbase + wrow * 64 + mt * 16 + quad * 4 + reg], v);
        }
    }
    // Col sums: reduce across quads (xor 16, 32).
    #pragma unroll
    for (int nt = 0; nt < 2; ++nt) {
        float v = colpart[nt];
        v += __shfl_xor(v, 16, 64);
        v += __shfl_xor(v, 32, 64);
        if (quad == 0)
            atomicAdd(&Acol[cbase + wcol * 32 + nt * 16 + col0], v);
    }
}

// ---- Kernel 4: loss = sum_i log(A_i + Col_{i+1} - ep_i) - p_i; out = -W*loss/N
__global__ __launch_bounds__(1024) void k_final(const float* __restrict__ Arow,
                                                const float* __restrict__ Acol,
                                                const float* __restrict__ p,
                                                const float* __restrict__ ep,
                                                float* __restrict__ out) {
    __shared__ float swred[16];
    float s = 0.0f;
    for (int i = threadIdx.x; i < N - 1; i += 1024) {
        float tt = Arow[i] + Acol[i + 1] - ep[i];
        s += __logf(tt) - p[i];
    }
    #pragma unroll
    for (int m = 1; m < 64; m <<= 1) s += __shfl_xor(s, m, 64);
    int lane = threadIdx.x & 63, wid = threadIdx.x >> 6;
    if (lane == 0) swred[wid] = s;
    __syncthreads();
    if (threadIdx.x == 0) {
        float tot = 0.0f;
        #pragma unroll
        for (int w = 0; w < 16; ++w) tot += swred[w];
        out[0] = -WEIGHT * tot / (float)N;
    }
}

extern "C" void kernel_launch(void* const* d_in, const int* in_sizes, int n_in,
                              void* d_out, int out_size, void* d_ws, size_t ws_size,
                              hipStream_t stream) {
    const float* x = (const float*)d_in[0];
    float* out = (float*)d_out;
    char* ws = (char*)d_ws;
    __hip_bfloat16* fb = (__hip_bfloat16*)ws;                  // N*D*2 = 2 MB
    float* p    = (float*)(ws + (size_t)N * D * 2);            // N floats
    float* ep   = p + N;
    float* Arow = ep + N;
    float* Acol = Arow + N;

    hipLaunchKernelGGL(k_norm,  dim3(2048), dim3(256),  0, stream, x, fb, Arow, Acol);
    hipLaunchKernelGGL(k_pos,   dim3(2048), dim3(256),  0, stream, fb, p, ep);
    hipLaunchKernelGGL(k_gram,  dim3(2080), dim3(512),  0, stream, fb, Arow, Acol);
    hipLaunchKernelGGL(k_final, dim3(1),    dim3(1024), 0, stream, Arow, Acol, p, ep, out);
}

// Round 3
// 107.107 us; speedup vs baseline: 1.1618x; 1.1226x over previous
//
#include <hip/hip_runtime.h>
#include <hip/hip_bf16.h>

#define N 8192
#define D 128
#define WEIGHT 0.01f
#define NTILES 64            // N / 128
#define NBLK 2080            // NTILES*(NTILES+1)/2

typedef __bf16 bf16x8 __attribute__((ext_vector_type(8)));
typedef float floatx4 __attribute__((ext_vector_type(4)));

// ---- Kernel 1: L2-normalize rows (fp32), store bf16.
__global__ __launch_bounds__(256) void k_norm(const float* __restrict__ x,
                                              __hip_bfloat16* __restrict__ fb) {
    int gid = blockIdx.x * 256 + threadIdx.x;   // 2048 blocks -> 8192 waves
    int row = gid >> 6;
    int lane = gid & 63;
    const float* xr = x + row * D;
    float a0 = xr[lane];
    float a1 = xr[lane + 64];
    float s = a0 * a0 + a1 * a1;
    #pragma unroll
    for (int m = 1; m < 64; m <<= 1) s += __shfl_xor(s, m, 64);
    float inv = 1.0f / fmaxf(sqrtf(s), 1e-12f);
    fb[row * D + lane]      = __float2bfloat16(a0 * inv);
    fb[row * D + lane + 64] = __float2bfloat16(a1 * inv);
}

// ---- Kernel 2: upper-triangle 128x128 tiles of sim = F F^T.
//      Per block: row partials (strict-upper exp sums) and col partials ->
//      LDS cross-wave reduce -> ONE coalesced 128-float store each (no atomics).
//      Also extracts p[i]=sim[i,i+1], ep[i]=exp(p[i]) in diag/superdiag tiles.
__global__ __launch_bounds__(512, 4) void k_gram(const __hip_bfloat16* __restrict__ fb,
                                                 float* __restrict__ Prow,
                                                 float* __restrict__ Pcol,
                                                 float* __restrict__ p,
                                                 float* __restrict__ ep) {
    // Decode triangular linear index -> (bi, bj), bj >= bi.
    int b = blockIdx.x;                  // 0 .. 2079
    int bi = (int)((2.0 * NTILES + 1.0 - sqrt((2.0 * NTILES + 1.0) * (2.0 * NTILES + 1.0) - 8.0 * (double)b)) * 0.5);
    while (bi * NTILES - bi * (bi - 1) / 2 > b) --bi;
    while ((bi + 1) * NTILES - (bi + 1) * bi / 2 <= b) ++bi;
    int bj = bi + (b - (bi * NTILES - bi * (bi - 1) / 2));

    __shared__ uint4 Ab[128 * 16];       // 128 rows x 128 bf16 (16 uint4), XOR-swizzled
    __shared__ uint4 Bb[128 * 16];
    __shared__ float PR[4][128];         // per-wcol row partials
    __shared__ float PC[2][128];         // per-wrow col partials
    const int t = threadIdx.x;
    const int rbase = bi * 128, cbase = bj * 128;
    const uint4* g = (const uint4*)fb;   // row stride = 16 uint4 (D=128 bf16)
    #pragma unroll
    for (int k = 0; k < 4; ++k) {
        int idx = t + k * 512;           // 0..2047
        int row = idx >> 4, c16 = idx & 15;
        int sw = c16 ^ (row & 15);       // XOR swizzle breaks 256B-stride bank aliasing
        Ab[row * 16 + sw] = g[(rbase + row) * 16 + c16];
        Bb[row * 16 + sw] = g[(cbase + row) * 16 + c16];
    }
    __syncthreads();

    const int lane = t & 63;
    const int wid  = t >> 6;             // 8 waves: 2x4 grid; wave tile 64 rows x 32 cols
    const int wrow = wid >> 2, wcol = wid & 3;
    const int col0 = lane & 15;
    const int quad = lane >> 4;

    floatx4 acc[4][2];
    #pragma unroll
    for (int a = 0; a < 4; ++a)
        #pragma unroll
        for (int c = 0; c < 2; ++c)
            acc[a][c] = (floatx4){0.0f, 0.0f, 0.0f, 0.0f};

    #pragma unroll
    for (int ks = 0; ks < 4; ++ks) {     // K = 128 = 4 x 32
        bf16x8 af[4], bfr[2];
        int j = ks * 4 + quad;           // uint4 chunk index within row
        int jsw = j ^ col0;              // (row & 15) == col0 for all fragment rows
        #pragma unroll
        for (int mt = 0; mt < 4; ++mt) {
            int rl = wrow * 64 + mt * 16 + col0;   // A[m=lane&15][k=quad*8+j]
            af[mt] = *(const bf16x8*)&Ab[rl * 16 + jsw];
        }
        #pragma unroll
        for (int nt = 0; nt < 2; ++nt) {
            int cl = wcol * 32 + nt * 16 + col0;   // B^T[n=lane&15][k]
            bfr[nt] = *(const bf16x8*)&Bb[cl * 16 + jsw];
        }
        #pragma unroll
        for (int mt = 0; mt < 4; ++mt)
            #pragma unroll
            for (int nt = 0; nt < 2; ++nt)
                acc[mt][nt] = __builtin_amdgcn_mfma_f32_16x16x32_bf16(af[mt], bfr[nt], acc[mt][nt], 0, 0, 0);
    }

    // Epilogue: e = exp(sim); strict-upper mask only needed near the diagonal.
    float rowpart[4][4];                 // [mt][reg] -> row = quad*4+reg
    float colpart[2];                    // [nt]      -> col = lane&15
    #pragma unroll
    for (int a = 0; a < 4; ++a)
        #pragma unroll
        for (int c = 0; c < 4; ++c) rowpart[a][c] = 0.0f;
    colpart[0] = colpart[1] = 0.0f;

    if (bj > bi + 1) {                   // fast path: all elements strictly upper
        #pragma unroll
        for (int mt = 0; mt < 4; ++mt)
            #pragma unroll
            for (int nt = 0; nt < 2; ++nt)
                #pragma unroll
                for (int reg = 0; reg < 4; ++reg) {
                    float e = __expf(acc[mt][nt][reg]);
                    rowpart[mt][reg] += e;
                    colpart[nt] += e;
                }
    } else {                             // diag / superdiag: mask + p extraction
        #pragma unroll
        for (int mt = 0; mt < 4; ++mt)
            #pragma unroll
            for (int nt = 0; nt < 2; ++nt)
                #pragma unroll
                for (int reg = 0; reg < 4; ++reg) {
                    int r = rbase + wrow * 64 + mt * 16 + quad * 4 + reg;  // C/D row
                    int c = cbase + wcol * 32 + nt * 16 + col0;            // C/D col
                    float v = acc[mt][nt][reg];
                    float e = __expf(v);
                    if (c == r + 1) { p[r] = v; ep[r] = e; }
                    e = (c > r) ? e : 0.0f;
                    rowpart[mt][reg] += e;
                    colpart[nt] += e;
                }
    }

    // Row sums: reduce across the 16 lanes of each quad (xor 1,2,4,8).
    #pragma unroll
    for (int mt = 0; mt < 4; ++mt) {
        #pragma unroll
        for (int reg = 0; reg < 4; ++reg) {
            float v = rowpart[mt][reg];
            v += __shfl_xor(v, 1, 64);
            v += __shfl_xor(v, 2, 64);
            v += __shfl_xor(v, 4, 64);
            v += __shfl_xor(v, 8, 64);
            if (col0 == 0)
                PR[wcol][wrow * 64 + mt * 16 + quad * 4 + reg] = v;
        }
    }
    // Col sums: reduce across quads (xor 16, 32).
    #pragma unroll
    for (int nt = 0; nt < 2; ++nt) {
        float v = colpart[nt];
        v += __shfl_xor(v, 16, 64);
        v += __shfl_xor(v, 32, 64);
        if (quad == 0)
            PC[wrow][wcol * 32 + nt * 16 + col0] = v;
    }
    __syncthreads();

    // One coalesced partial store per block (no atomics).
    if (t < 128) {
        Prow[(size_t)b * 128 + t] = PR[0][t] + PR[1][t] + PR[2][t] + PR[3][t];
    } else if (t < 256) {
        int c = t - 128;
        Pcol[(size_t)b * 128 + c] = PC[0][c] + PC[1][c];
    }
}

// ---- Kernel 3: gather partials -> U[r] (strict-upper row sums), L[c] (col sums).
__global__ __launch_bounds__(256) void k_reduce(const float* __restrict__ Prow,
                                                const float* __restrict__ Pcol,
                                                float* __restrict__ U,
                                                float* __restrict__ L) {
    int tile = blockIdx.x;               // 0..63
    int tid = threadIdx.x;
    int base_t = tile * NTILES - tile * (tile - 1) / 2;
    if (tid < 128) {
        float s = 0.0f;
        for (int bj = tile; bj < NTILES; ++bj)
            s += Prow[(size_t)(base_t + bj - tile) * 128 + tid];
        U[tile * 128 + tid] = s;
    } else {
        int c = tid - 128;
        float s = 0.0f;
        for (int bi = 0; bi <= tile; ++bi) {
            int bb = bi * NTILES - bi * (bi - 1) / 2 + (tile - bi);
            s += Pcol[(size_t)bb * 128 + c];
        }
        L[tile * 128 + c] = s;
    }
}

// ---- Kernel 4: loss = sum_i log(U_i + L_{i+1} - ep_i) - p_i; out = -W*loss/N
__global__ __launch_bounds__(1024) void k_final(const float* __restrict__ U,
                                                const float* __restrict__ L,
                                                const float* __restrict__ p,
                                                const float* __restrict__ ep,
                                                float* __restrict__ out) {
    __shared__ float swred[16];
    float s = 0.0f;
    for (int i = threadIdx.x; i < N - 1; i += 1024) {
        float tt = U[i] + L[i + 1] - ep[i];
        s += __logf(tt) - p[i];
    }
    #pragma unroll
    for (int m = 1; m < 64; m <<= 1) s += __shfl_xor(s, m, 64);
    int lane = threadIdx.x & 63, wid = threadIdx.x >> 6;
    if (lane == 0) swred[wid] = s;
    __syncthreads();
    if (threadIdx.x == 0) {
        float tot = 0.0f;
        #pragma unroll
        for (int w = 0; w < 16; ++w) tot += swred[w];
        out[0] = -WEIGHT * tot / (float)N;
    }
}

extern "C" void kernel_launch(void* const* d_in, const int* in_sizes, int n_in,
                              void* d_out, int out_size, void* d_ws, size_t ws_size,
                              hipStream_t stream) {
    const float* x = (const float*)d_in[0];
    float* out = (float*)d_out;
    char* ws = (char*)d_ws;
    __hip_bfloat16* fb = (__hip_bfloat16*)ws;                  // N*D*2 = 2 MB
    float* p    = (float*)(ws + (size_t)N * D * 2);            // N floats
    float* ep   = p + N;
    float* U    = ep + N;
    float* L    = U + N;
    float* Prow = L + N;                                       // NBLK*128 floats
    float* Pcol = Prow + (size_t)NBLK * 128;

    hipLaunchKernelGGL(k_norm,   dim3(2048), dim3(256),  0, stream, x, fb);
    hipLaunchKernelGGL(k_gram,   dim3(NBLK), dim3(512),  0, stream, fb, Prow, Pcol, p, ep);
    hipLaunchKernelGGL(k_reduce, dim3(64),   dim3(256),  0, stream, Prow, Pcol, U, L);
    hipLaunchKernelGGL(k_final,  dim3(1),    dim3(1024), 0, stream, U, L, p, ep, out);
}